// Round 14
// baseline (534.218 us; speedup 1.0000x reference)
//
#include <hip/hip_runtime.h>
#include <hip/hip_bf16.h>
#include <hip/hip_fp16.h>

#define N_NODES 50000
#define N_EDGES 400000
#define IN_DIM_ 128
#define WIDTH_ 256
#define HEADS_ 4
#define HID_ 64
#define NUM_GRAPHS_ 256
#define NEG_SLOPE_ 0.2f
#define HROW 50048  // padded rows (multiple of 128)

using s16x8 = __attribute__((ext_vector_type(8))) short;
using f32x4 = __attribute__((ext_vector_type(4))) float;

// split f32 into bf16 hi + bf16 lo (truncation; residual captured exactly)
__device__ inline void split1(float x, short& h, short& l) {
    unsigned int u = __float_as_uint(x);
    h = (short)(u >> 16);
    float hf = __uint_as_float(u & 0xffff0000u);
    float r = x - hf;  // exact
    l = (short)(__float_as_uint(r) >> 16);
}
__device__ inline float join1(short h, short l) {
    return __uint_as_float(((unsigned int)(unsigned short)h) << 16) +
           __uint_as_float(((unsigned int)(unsigned short)l) << 16);
}
__device__ inline float h2f(unsigned short u) {
    return __half2float(__ushort_as_half(u));
}
__device__ inline float lrelu(float x) { return (x >= 0.f) ? x : NEG_SLOPE_ * x; }

// ---------------- CSR build ----------------
__global__ void hist_kernel(const int* __restrict__ dst, int* __restrict__ deg) {
    int e = blockIdx.x * blockDim.x + threadIdx.x;
    if (e < N_EDGES) atomicAdd(&deg[dst[e]], 1);
}

__global__ void scan1_kernel(const int* __restrict__ deg, int* __restrict__ rowptr,
                             int* __restrict__ partials) {
    __shared__ int s[256];
    int t = threadIdx.x;
    int gid = blockIdx.x * 256 + t;
    int v = (gid < N_NODES) ? deg[gid] : 0;
    s[t] = v;
    __syncthreads();
    for (int off = 1; off < 256; off <<= 1) {
        int x = 0;
        if (t >= off) x = s[t - off];
        __syncthreads();
        if (t >= off) s[t] += x;
        __syncthreads();
    }
    if (gid < N_NODES) rowptr[gid] = s[t] - v;
    if (t == 255) partials[blockIdx.x] = s[255];
}

__global__ void scan2_kernel(int* __restrict__ partials, int nb) {
    __shared__ int s[256];
    int t = threadIdx.x;
    int v = (t < nb) ? partials[t] : 0;
    s[t] = v;
    __syncthreads();
    for (int off = 1; off < 256; off <<= 1) {
        int x = 0;
        if (t >= off) x = s[t - off];
        __syncthreads();
        if (t >= off) s[t] += x;
        __syncthreads();
    }
    if (t < nb) partials[t] = s[t] - v;
}

__global__ void scan3_kernel(int* __restrict__ rowptr, const int* __restrict__ partials) {
    int gid = blockIdx.x * 256 + threadIdx.x;
    if (gid < N_NODES) rowptr[gid] += partials[blockIdx.x];
    if (gid == 0) rowptr[N_NODES] = N_EDGES;
}

__global__ void scatter_kernel(const int* __restrict__ src, const int* __restrict__ dst,
                               const int* __restrict__ rowptr, int* __restrict__ cursor,
                               int* __restrict__ csr_src, int* __restrict__ csr_dst) {
    int e = blockIdx.x * blockDim.x + threadIdx.x;
    if (e < N_EDGES) {
        int d = dst[e];
        int pos = rowptr[d] + atomicAdd(&cursor[d], 1);
        csr_src[pos] = src[e];
        csr_dst[pos] = d;
    }
}

// ---------------- input splits ----------------
template <int K>
__global__ void split4_kernel(const float* __restrict__ in, short* __restrict__ hi,
                              short* __restrict__ lo) {
    int idx = blockIdx.x * blockDim.x + threadIdx.x;      // float4 index
    if (idx >= HROW * K / 4) return;
    int e0 = idx << 2;
    int row = e0 / K;
    float4 v = make_float4(0.f, 0.f, 0.f, 0.f);
    if (row < N_NODES) v = *(const float4*)&in[e0];
    short4 h, l;
    split1(v.x, h.x, l.x);
    split1(v.y, h.y, l.y);
    split1(v.z, h.z, l.z);
    split1(v.w, h.w, l.w);
    *(short4*)&hi[e0] = h;
    *(short4*)&lo[e0] = l;
}

// W (f32 [K,256]) -> Wt hi/lo (bf16 [256,K])
__global__ void wsplit_kernel(const float* __restrict__ W, short* __restrict__ Whi,
                              short* __restrict__ Wlo, int K) {
    int idx = blockIdx.x * blockDim.x + threadIdx.x;
    if (idx >= K * 256) return;
    int k = idx >> 8, n = idx & 255;
    short h, l;
    split1(W[idx], h, l);
    Whi[n * K + k] = h;
    Wlo[n * K + k] = l;
}

// ---------------- MFMA GEMM: G[M,256] = fp16(A[M,K] @ Wt[N,K]^T) (bf16x3) ----
// 1 wave per block, 64x64 tile, register double-buffered K pipeline.
#define LOADF(AH, AV, BH, BV, KK)                                              \
    {                                                                          \
        _Pragma("unroll") for (int r = 0; r < 4; ++r) {                        \
            size_t ai = (size_t)(row0 + r * 16 + lr) * K + (KK) + lk;          \
            AH[r] = *(const s16x8*)&Ahi[ai];                                   \
            AV[r] = *(const s16x8*)&Alo[ai];                                   \
            size_t bi = (size_t)(col0 + r * 16 + lr) * K + (KK) + lk;          \
            BH[r] = *(const s16x8*)&Bhi[bi];                                   \
            BV[r] = *(const s16x8*)&Blo[bi];                                   \
        }                                                                      \
    }

#define MFMAS(AH, AV, BH, BV)                                                  \
    {                                                                          \
        _Pragma("unroll") for (int i = 0; i < 4; ++i)                          \
            _Pragma("unroll") for (int j = 0; j < 4; ++j) {                    \
            acc[i][j] =                                                        \
                __builtin_amdgcn_mfma_f32_16x16x32_bf16(AH[i], BH[j], acc[i][j], 0, 0, 0); \
            acc[i][j] =                                                        \
                __builtin_amdgcn_mfma_f32_16x16x32_bf16(AH[i], BV[j], acc[i][j], 0, 0, 0); \
            acc[i][j] =                                                        \
                __builtin_amdgcn_mfma_f32_16x16x32_bf16(AV[i], BH[j], acc[i][j], 0, 0, 0); \
        }                                                                      \
    }

template <int K>
__global__ __launch_bounds__(64, 2) void mfma_gemm(const short* __restrict__ Ahi,
                                                   const short* __restrict__ Alo,
                                                   const short* __restrict__ Bhi,
                                                   const short* __restrict__ Blo,
                                                   __half* __restrict__ G) {
    const int lane = threadIdx.x;
    const int row0 = blockIdx.x * 64;
    const int col0 = blockIdx.y * 64;
    const int lr = lane & 15;
    const int lk = (lane >> 4) << 3;

    f32x4 acc[4][4] = {};
    s16x8 ah0[4], av0[4], bh0[4], bv0[4];
    s16x8 ah1[4], av1[4], bh1[4], bv1[4];

    LOADF(ah0, av0, bh0, bv0, 0);
#pragma unroll
    for (int kk = 0; kk < K; kk += 64) {
        LOADF(ah1, av1, bh1, bv1, kk + 32);
        MFMAS(ah0, av0, bh0, bv0);
        if (kk + 64 < K) LOADF(ah0, av0, bh0, bv0, kk + 64);
        MFMAS(ah1, av1, bh1, bv1);
    }
    // C/D layout: col = lane&15, row = (lane>>4)*4 + reg
    const int rb = (lane >> 4) << 2;
#pragma unroll
    for (int i = 0; i < 4; ++i)
#pragma unroll
        for (int q = 0; q < 4; ++q) {
            int r = row0 + i * 16 + rb + q;
#pragma unroll
            for (int j = 0; j < 4; ++j)
                G[(size_t)r * WIDTH_ + col0 + j * 16 + lr] = __float2half(acc[i][j][q]);
        }
}

// ---------------- attention logits: al_s/al_d [N,4] (fp16 h) ----------------
__global__ void al_kernel(const __half* __restrict__ hg, const float* __restrict__ a_src,
                          const float* __restrict__ a_dst, float* __restrict__ als,
                          float* __restrict__ ald) {
    int wid = (blockIdx.x * blockDim.x + threadIdx.x) >> 6;
    int lane = threadIdx.x & 63;
    if (wid >= N_NODES) return;
    ushort4 u = *(const ushort4*)&hg[(size_t)wid * WIDTH_ + (lane << 2)];
    float h0 = h2f(u.x), h1 = h2f(u.y), h2 = h2f(u.z), h3 = h2f(u.w);
    int hd = lane >> 4;
    int j0 = (lane & 15) << 2;
    const float4 as = *(const float4*)&a_src[hd * HID_ + j0];
    const float4 ad = *(const float4*)&a_dst[hd * HID_ + j0];
    float ps = h0 * as.x + h1 * as.y + h2 * as.z + h3 * as.w;
    float pd = h0 * ad.x + h1 * ad.y + h2 * ad.z + h3 * ad.w;
    for (int off = 1; off < 16; off <<= 1) {
        ps += __shfl_xor(ps, off);
        pd += __shfl_xor(pd, off);
    }
    if ((lane & 15) == 0) {
        als[wid * 4 + hd] = ps;
        ald[wid * 4 + hd] = pd;
    }
}

// -------- edge softmax numerators in CSR order: p[i][h] = exp(lrelu(als+ald)) --------
__global__ void edge_logit_kernel(const float* __restrict__ als, const float* __restrict__ ald,
                                  const int* __restrict__ csr_src, const int* __restrict__ csr_dst,
                                  float* __restrict__ p_arr) {
    int i = blockIdx.x * blockDim.x + threadIdx.x;
    if (i >= N_EDGES) return;
    int s = csr_src[i], d = csr_dst[i];
    float4 as = *(const float4*)&als[s * 4];
    float4 ad = *(const float4*)&ald[d * 4];
    float4 ev;
    ev.x = __expf(lrelu(as.x + ad.x));
    ev.y = __expf(lrelu(as.y + ad.y));
    ev.z = __expf(lrelu(as.z + ad.z));
    ev.w = __expf(lrelu(as.w + ad.w));
    *(float4*)&p_arr[i * 4] = ev;
}

// ------- per-dst single-pass aggregation + bias + ELU; writes hi/lo bf16 ----
__global__ void aggregate_kernel(const __half* __restrict__ hg, const float* __restrict__ als,
                                 const float* __restrict__ ald_, const int* __restrict__ rowptr,
                                 const int* __restrict__ csr_src, const float* __restrict__ p_arr,
                                 const float* __restrict__ bias, short* __restrict__ ohi,
                                 short* __restrict__ olo) {
    int n = (blockIdx.x * blockDim.x + threadIdx.x) >> 6;
    int lane = threadIdx.x & 63;
    if (n >= N_NODES) return;
    int hd = lane >> 4;
    int c0 = lane << 2;

    float p_self = __expf(lrelu(als[n * 4 + hd] + ald_[n * 4 + hd]));
    ushort4 su = *(const ushort4*)&hg[(size_t)n * WIDTH_ + c0];
    float a0 = p_self * h2f(su.x), a1 = p_self * h2f(su.y);
    float a2 = p_self * h2f(su.z), a3 = p_self * h2f(su.w);
    float denom = p_self;

    int rs = rowptr[n], re = rowptr[n + 1];
    int i = rs;
    float w0 = 0.f, w1 = 0.f, w2 = 0.f, w3 = 0.f;
    float x0 = 0.f, x1 = 0.f, x2 = 0.f, x3 = 0.f;
    float y0 = 0.f, y1 = 0.f, y2 = 0.f, y3 = 0.f;
    float z0 = 0.f, z1 = 0.f, z2 = 0.f, z3 = 0.f;
    float v0 = 0.f, v1 = 0.f, v2 = 0.f, v3 = 0.f;
    for (; i + 4 <= re; i += 4) {
        int s0 = csr_src[i + 0], s1 = csr_src[i + 1];
        int s2 = csr_src[i + 2], s3 = csr_src[i + 3];
        float p0 = p_arr[(i + 0) * 4 + hd], p1 = p_arr[(i + 1) * 4 + hd];
        float p2 = p_arr[(i + 2) * 4 + hd], p3 = p_arr[(i + 3) * 4 + hd];
        ushort4 u0 = *(const ushort4*)&hg[(size_t)s0 * WIDTH_ + c0];
        ushort4 u1 = *(const ushort4*)&hg[(size_t)s1 * WIDTH_ + c0];
        ushort4 u2 = *(const ushort4*)&hg[(size_t)s2 * WIDTH_ + c0];
        ushort4 u3 = *(const ushort4*)&hg[(size_t)s3 * WIDTH_ + c0];
        x0 += p0 * h2f(u0.x); y0 += p0 * h2f(u0.y); z0 += p0 * h2f(u0.z); v0 += p0 * h2f(u0.w);
        x1 += p1 * h2f(u1.x); y1 += p1 * h2f(u1.y); z1 += p1 * h2f(u1.z); v1 += p1 * h2f(u1.w);
        x2 += p2 * h2f(u2.x); y2 += p2 * h2f(u2.y); z2 += p2 * h2f(u2.z); v2 += p2 * h2f(u2.w);
        x3 += p3 * h2f(u3.x); y3 += p3 * h2f(u3.y); z3 += p3 * h2f(u3.z); v3 += p3 * h2f(u3.w);
        w0 += p0; w1 += p1; w2 += p2; w3 += p3;
    }
    for (; i < re; ++i) {
        int s = csr_src[i];
        float p = p_arr[i * 4 + hd];
        ushort4 u = *(const ushort4*)&hg[(size_t)s * WIDTH_ + c0];
        x0 += p * h2f(u.x); y0 += p * h2f(u.y); z0 += p * h2f(u.z); v0 += p * h2f(u.w);
        w0 += p;
    }
    a0 += (x0 + x1) + (x2 + x3);
    a1 += (y0 + y1) + (y2 + y3);
    a2 += (z0 + z1) + (z2 + z3);
    a3 += (v0 + v1) + (v2 + v3);
    denom += (w0 + w1) + (w2 + w3);

    float inv = 1.0f / (denom + 1e-16f);
    float r0 = a0 * inv + bias[c0 + 0];
    float r1 = a1 * inv + bias[c0 + 1];
    float r2 = a2 * inv + bias[c0 + 2];
    float r3 = a3 * inv + bias[c0 + 3];
    r0 = (r0 > 0.f) ? r0 : (__expf(r0) - 1.f);
    r1 = (r1 > 0.f) ? r1 : (__expf(r1) - 1.f);
    r2 = (r2 > 0.f) ? r2 : (__expf(r2) - 1.f);
    r3 = (r3 > 0.f) ? r3 : (__expf(r3) - 1.f);
    short4 h, l;
    split1(r0, h.x, l.x);
    split1(r1, h.y, l.y);
    split1(r2, h.z, l.z);
    split1(r3, h.w, l.w);
    *(short4*)&ohi[(size_t)n * WIDTH_ + c0] = h;
    *(short4*)&olo[(size_t)n * WIDTH_ + c0] = l;
}

// ---------------- final pool ----------------
__global__ void out_init_kernel(const float* __restrict__ lin_b, float* __restrict__ out) {
    out[threadIdx.x] = lin_b[0];
}

__global__ void pool_kernel(const short* __restrict__ hhi, const short* __restrict__ hlo,
                            const float* __restrict__ lin_w, const int* __restrict__ batch,
                            float* __restrict__ out) {
    __shared__ float acc[NUM_GRAPHS_];
    int t = threadIdx.x;
    acc[t] = 0.f;
    __syncthreads();
    int wid = t >> 6, lane = t & 63;
    int n0 = blockIdx.x * 64;
    float4 wv = *(const float4*)&lin_w[lane << 2];
    for (int n = n0 + wid; n < n0 + 64; n += 4) {
        if (n >= N_NODES) break;
        short4 vh = *(const short4*)&hhi[(size_t)n * WIDTH_ + (lane << 2)];
        short4 vl = *(const short4*)&hlo[(size_t)n * WIDTH_ + (lane << 2)];
        float p = join1(vh.x, vl.x) * wv.x + join1(vh.y, vl.y) * wv.y +
                  join1(vh.z, vl.z) * wv.z + join1(vh.w, vl.w) * wv.w;
        for (int off = 1; off < 64; off <<= 1) p += __shfl_xor(p, off);
        if (lane == 0) atomicAdd(&acc[batch[n]], p);
    }
    __syncthreads();
    float v = acc[t];
    if (v != 0.f) atomicAdd(&out[t], v);
}

extern "C" void kernel_launch(void* const* d_in, const int* in_sizes, int n_in,
                              void* d_out, int out_size, void* d_ws, size_t ws_size,
                              hipStream_t stream) {
    const float* x = (const float*)d_in[0];
    const int* edge_index = (const int*)d_in[1];
    const int* batch = (const int*)d_in[3];
    const float* W0 = (const float*)d_in[4];
    const float* a_src0 = (const float*)d_in[5];
    const float* a_dst0 = (const float*)d_in[6];
    const float* b0 = (const float*)d_in[7];
    const float* W1 = (const float*)d_in[8];
    const float* a_src1 = (const float*)d_in[9];
    const float* a_dst1 = (const float*)d_in[10];
    const float* b1 = (const float*)d_in[11];
    const float* W2 = (const float*)d_in[12];
    const float* a_src2 = (const float*)d_in[13];
    const float* a_dst2 = (const float*)d_in[14];
    const float* b2 = (const float*)d_in[15];
    const float* lin_w = (const float*)d_in[16];
    const float* lin_b = (const float*)d_in[17];
    float* out = (float*)d_out;

    const int* e_src = edge_index;
    const int* e_dst = edge_index + N_EDGES;

    // ---- workspace layout ----
    char* p = (char*)d_ws;
    __half* hG = (__half*)p;              p += (size_t)HROW * WIDTH_ * 2;   // 25.6 MB
    short* hBhi = (short*)p;              p += (size_t)HROW * WIDTH_ * 2;   // 25.6 MB
    short* hBlo = (short*)p;              p += (size_t)HROW * WIDTH_ * 2;   // 25.6 MB
    short* Wt0h = (short*)p;              p += 256 * IN_DIM_ * 2;
    short* Wt0l = (short*)p;              p += 256 * IN_DIM_ * 2;
    short* Wt1h = (short*)p;              p += 256 * WIDTH_ * 2;
    short* Wt1l = (short*)p;              p += 256 * WIDTH_ * 2;
    short* Wt2h = (short*)p;              p += 256 * WIDTH_ * 2;
    short* Wt2l = (short*)p;              p += 256 * WIDTH_ * 2;
    float* als = (float*)p;               p += (size_t)HROW * 4 * 4;
    float* ald = (float*)p;               p += (size_t)HROW * 4 * 4;
    float* p_arr = (float*)p;             p += (size_t)N_EDGES * 4 * 4;     // 6.4 MB
    int* deg = (int*)p;                   p += HROW * 4;
    int* rowptr = (int*)p;                p += (HROW + 4) * 4;
    int* cursor = (int*)p;                p += HROW * 4;
    int* csr_src = (int*)p;               p += (size_t)N_EDGES * 4;
    int* csr_dst = (int*)p;               p += (size_t)N_EDGES * 4;
    int* partials = (int*)p;              p += 256 * 4;
    // x splits alias hBhi (dead before aggregate layer 0 writes hB)
    short* xhi = hBhi;
    short* xlo = hBhi + (size_t)HROW * IN_DIM_;

    // ---- CSR build ----
    hipMemsetAsync(deg, 0, HROW * sizeof(int), stream);
    hipMemsetAsync(cursor, 0, HROW * sizeof(int), stream);
    hist_kernel<<<(N_EDGES + 255) / 256, 256, 0, stream>>>(e_dst, deg);
    const int NB1 = (N_NODES + 255) / 256;
    scan1_kernel<<<NB1, 256, 0, stream>>>(deg, rowptr, partials);
    scan2_kernel<<<1, 256, 0, stream>>>(partials, NB1);
    scan3_kernel<<<NB1, 256, 0, stream>>>(rowptr, partials);
    scatter_kernel<<<(N_EDGES + 255) / 256, 256, 0, stream>>>(e_src, e_dst, rowptr, cursor,
                                                              csr_src, csr_dst);

    // ---- weight splits ----
    wsplit_kernel<<<IN_DIM_, 256, 0, stream>>>(W0, Wt0h, Wt0l, IN_DIM_);
    wsplit_kernel<<<WIDTH_, 256, 0, stream>>>(W1, Wt1h, Wt1l, WIDTH_);
    wsplit_kernel<<<WIDTH_, 256, 0, stream>>>(W2, Wt2h, Wt2l, WIDTH_);
    // ---- x split ----
    split4_kernel<IN_DIM_><<<(HROW * IN_DIM_ / 4 + 255) / 256, 256, 0, stream>>>(x, xhi, xlo);

    dim3 ggrid(HROW / 64, WIDTH_ / 64);  // (782, 4), 1 wave per block
    const int NWB = (N_NODES + 3) / 4;
    const int NEB = (N_EDGES + 255) / 256;

    // layer 0
    mfma_gemm<IN_DIM_><<<ggrid, 64, 0, stream>>>(xhi, xlo, Wt0h, Wt0l, hG);
    al_kernel<<<NWB, 256, 0, stream>>>(hG, a_src0, a_dst0, als, ald);
    edge_logit_kernel<<<NEB, 256, 0, stream>>>(als, ald, csr_src, csr_dst, p_arr);
    aggregate_kernel<<<NWB, 256, 0, stream>>>(hG, als, ald, rowptr, csr_src, p_arr, b0, hBhi,
                                              hBlo);
    // layer 1
    mfma_gemm<WIDTH_><<<ggrid, 64, 0, stream>>>(hBhi, hBlo, Wt1h, Wt1l, hG);
    al_kernel<<<NWB, 256, 0, stream>>>(hG, a_src1, a_dst1, als, ald);
    edge_logit_kernel<<<NEB, 256, 0, stream>>>(als, ald, csr_src, csr_dst, p_arr);
    aggregate_kernel<<<NWB, 256, 0, stream>>>(hG, als, ald, rowptr, csr_src, p_arr, b1, hBhi,
                                              hBlo);
    // layer 2
    mfma_gemm<WIDTH_><<<ggrid, 64, 0, stream>>>(hBhi, hBlo, Wt2h, Wt2l, hG);
    al_kernel<<<NWB, 256, 0, stream>>>(hG, a_src2, a_dst2, als, ald);
    edge_logit_kernel<<<NEB, 256, 0, stream>>>(als, ald, csr_src, csr_dst, p_arr);
    aggregate_kernel<<<NWB, 256, 0, stream>>>(hG, als, ald, rowptr, csr_src, p_arr, b2, hBhi,
                                              hBlo);

    // ---- pool + linear ----
    out_init_kernel<<<1, 256, 0, stream>>>(lin_b, out);
    pool_kernel<<<(N_NODES + 63) / 64, 256, 0, stream>>>(hBhi, hBlo, lin_w, batch, out);
}

// Round 16
// 494.618 us; speedup vs baseline: 1.0801x; 1.0801x over previous
//
#include <hip/hip_runtime.h>
#include <hip/hip_bf16.h>
#include <hip/hip_fp16.h>

#define N_NODES 50000
#define N_EDGES 400000
#define IN_DIM_ 128
#define WIDTH_ 256
#define HEADS_ 4
#define HID_ 64
#define NUM_GRAPHS_ 256
#define NEG_SLOPE_ 0.2f
#define HROW 50048  // padded rows (multiple of 128)

using s16x8 = __attribute__((ext_vector_type(8))) short;
using f32x4 = __attribute__((ext_vector_type(4))) float;

// split f32 into bf16 hi + bf16 lo (truncation; residual captured exactly)
__device__ inline void split1(float x, short& h, short& l) {
    unsigned int u = __float_as_uint(x);
    h = (short)(u >> 16);
    float hf = __uint_as_float(u & 0xffff0000u);
    float r = x - hf;  // exact
    l = (short)(__float_as_uint(r) >> 16);
}
__device__ inline float join1(short h, short l) {
    return __uint_as_float(((unsigned int)(unsigned short)h) << 16) +
           __uint_as_float(((unsigned int)(unsigned short)l) << 16);
}
__device__ inline float h2f(unsigned short u) {
    return __half2float(__ushort_as_half(u));
}
__device__ inline float lrelu(float x) { return (x >= 0.f) ? x : NEG_SLOPE_ * x; }

// ---------------- CSR build ----------------
__global__ void hist_kernel(const int* __restrict__ dst, int* __restrict__ deg) {
    int e = blockIdx.x * blockDim.x + threadIdx.x;
    if (e < N_EDGES) atomicAdd(&deg[dst[e]], 1);
}

__global__ void scan1_kernel(const int* __restrict__ deg, int* __restrict__ rowptr,
                             int* __restrict__ partials) {
    __shared__ int s[256];
    int t = threadIdx.x;
    int gid = blockIdx.x * 256 + t;
    int v = (gid < N_NODES) ? deg[gid] : 0;
    s[t] = v;
    __syncthreads();
    for (int off = 1; off < 256; off <<= 1) {
        int x = 0;
        if (t >= off) x = s[t - off];
        __syncthreads();
        if (t >= off) s[t] += x;
        __syncthreads();
    }
    if (gid < N_NODES) rowptr[gid] = s[t] - v;
    if (t == 255) partials[blockIdx.x] = s[255];
}

__global__ void scan2_kernel(int* __restrict__ partials, int nb) {
    __shared__ int s[256];
    int t = threadIdx.x;
    int v = (t < nb) ? partials[t] : 0;
    s[t] = v;
    __syncthreads();
    for (int off = 1; off < 256; off <<= 1) {
        int x = 0;
        if (t >= off) x = s[t - off];
        __syncthreads();
        if (t >= off) s[t] += x;
        __syncthreads();
    }
    if (t < nb) partials[t] = s[t] - v;
}

__global__ void scan3_kernel(int* __restrict__ rowptr, const int* __restrict__ partials) {
    int gid = blockIdx.x * 256 + threadIdx.x;
    if (gid < N_NODES) rowptr[gid] += partials[blockIdx.x];
    if (gid == 0) rowptr[N_NODES] = N_EDGES;
}

__global__ void scatter_kernel(const int* __restrict__ src, const int* __restrict__ dst,
                               const int* __restrict__ rowptr, int* __restrict__ cursor,
                               int* __restrict__ csr_src, int* __restrict__ csr_dst) {
    int e = blockIdx.x * blockDim.x + threadIdx.x;
    if (e < N_EDGES) {
        int d = dst[e];
        int pos = rowptr[d] + atomicAdd(&cursor[d], 1);
        csr_src[pos] = src[e];
        csr_dst[pos] = d;
    }
}

// ---------------- input splits ----------------
template <int K>
__global__ void split4_kernel(const float* __restrict__ in, short* __restrict__ hi,
                              short* __restrict__ lo) {
    int idx = blockIdx.x * blockDim.x + threadIdx.x;      // float4 index
    if (idx >= HROW * K / 4) return;
    int e0 = idx << 2;
    int row = e0 / K;
    float4 v = make_float4(0.f, 0.f, 0.f, 0.f);
    if (row < N_NODES) v = *(const float4*)&in[e0];
    short4 h, l;
    split1(v.x, h.x, l.x);
    split1(v.y, h.y, l.y);
    split1(v.z, h.z, l.z);
    split1(v.w, h.w, l.w);
    *(short4*)&hi[e0] = h;
    *(short4*)&lo[e0] = l;
}

// W (f32 [K,256]) -> Wt hi/lo (bf16 [256,K])
__global__ void wsplit_kernel(const float* __restrict__ W, short* __restrict__ Whi,
                              short* __restrict__ Wlo, int K) {
    int idx = blockIdx.x * blockDim.x + threadIdx.x;
    if (idx >= K * 256) return;
    int k = idx >> 8, n = idx & 255;
    short h, l;
    split1(W[idx], h, l);
    Whi[n * K + k] = h;
    Wlo[n * K + k] = l;
}

// ---------------- MFMA GEMM: G[M,256] = fp16(A[M,K] @ Wt[N,K]^T) (bf16x3) ----
// 1 wave per block, 64x64 tile, register double-buffered K pipeline.
// Bijective XCD swizzle: each XCD gets a contiguous work chunk; work decoded
// col-fastest so the 4 col-blocks of the same A rows share that XCD's L2.
#define LOADF(AH, AV, BH, BV, KK)                                              \
    {                                                                          \
        _Pragma("unroll") for (int r = 0; r < 4; ++r) {                        \
            size_t ai = (size_t)(row0 + r * 16 + lr) * K + (KK) + lk;          \
            AH[r] = *(const s16x8*)&Ahi[ai];                                   \
            AV[r] = *(const s16x8*)&Alo[ai];                                   \
            size_t bi = (size_t)(col0 + r * 16 + lr) * K + (KK) + lk;          \
            BH[r] = *(const s16x8*)&Bhi[bi];                                   \
            BV[r] = *(const s16x8*)&Blo[bi];                                   \
        }                                                                      \
    }

#define MFMAS(AH, AV, BH, BV)                                                  \
    {                                                                          \
        _Pragma("unroll") for (int i = 0; i < 4; ++i)                          \
            _Pragma("unroll") for (int j = 0; j < 4; ++j) {                    \
            acc[i][j] =                                                        \
                __builtin_amdgcn_mfma_f32_16x16x32_bf16(AH[i], BH[j], acc[i][j], 0, 0, 0); \
            acc[i][j] =                                                        \
                __builtin_amdgcn_mfma_f32_16x16x32_bf16(AH[i], BV[j], acc[i][j], 0, 0, 0); \
            acc[i][j] =                                                        \
                __builtin_amdgcn_mfma_f32_16x16x32_bf16(AV[i], BH[j], acc[i][j], 0, 0, 0); \
        }                                                                      \
    }

#define NWG_GEMM (HROW / 64 * 4)          // 3128, divisible by 8
#define WG_PER_XCD (NWG_GEMM / 8)         // 391

template <int K>
__global__ __launch_bounds__(64, 2) void mfma_gemm(const short* __restrict__ Ahi,
                                                   const short* __restrict__ Alo,
                                                   const short* __restrict__ Bhi,
                                                   const short* __restrict__ Blo,
                                                   __half* __restrict__ G) {
    const int lane = threadIdx.x;
    // XCD-contiguous work chunks: hw block bid lands on XCD bid%8.
    const int work = (blockIdx.x & 7) * WG_PER_XCD + (blockIdx.x >> 3);
    const int row0 = (work >> 2) * 64;
    const int col0 = (work & 3) * 64;
    const int lr = lane & 15;
    const int lk = (lane >> 4) << 3;

    f32x4 acc[4][4] = {};
    s16x8 ah0[4], av0[4], bh0[4], bv0[4];
    s16x8 ah1[4], av1[4], bh1[4], bv1[4];

    LOADF(ah0, av0, bh0, bv0, 0);
#pragma unroll
    for (int kk = 0; kk < K; kk += 64) {
        LOADF(ah1, av1, bh1, bv1, kk + 32);
        MFMAS(ah0, av0, bh0, bv0);
        if (kk + 64 < K) LOADF(ah0, av0, bh0, bv0, kk + 64);
        MFMAS(ah1, av1, bh1, bv1);
    }
    // C/D layout: col = lane&15, row = (lane>>4)*4 + reg
    const int rb = (lane >> 4) << 2;
#pragma unroll
    for (int i = 0; i < 4; ++i)
#pragma unroll
        for (int q = 0; q < 4; ++q) {
            int r = row0 + i * 16 + rb + q;
#pragma unroll
            for (int j = 0; j < 4; ++j)
                G[(size_t)r * WIDTH_ + col0 + j * 16 + lr] = __float2half(acc[i][j][q]);
        }
}

// ---------------- attention logits: al_s/al_d [N,4] (fp16 h) ----------------
__global__ void al_kernel(const __half* __restrict__ hg, const float* __restrict__ a_src,
                          const float* __restrict__ a_dst, float* __restrict__ als,
                          float* __restrict__ ald) {
    int wid = (blockIdx.x * blockDim.x + threadIdx.x) >> 6;
    int lane = threadIdx.x & 63;
    if (wid >= N_NODES) return;
    ushort4 u = *(const ushort4*)&hg[(size_t)wid * WIDTH_ + (lane << 2)];
    float h0 = h2f(u.x), h1 = h2f(u.y), h2 = h2f(u.z), h3 = h2f(u.w);
    int hd = lane >> 4;
    int j0 = (lane & 15) << 2;
    const float4 as = *(const float4*)&a_src[hd * HID_ + j0];
    const float4 ad = *(const float4*)&a_dst[hd * HID_ + j0];
    float ps = h0 * as.x + h1 * as.y + h2 * as.z + h3 * as.w;
    float pd = h0 * ad.x + h1 * ad.y + h2 * ad.z + h3 * ad.w;
    for (int off = 1; off < 16; off <<= 1) {
        ps += __shfl_xor(ps, off);
        pd += __shfl_xor(pd, off);
    }
    if ((lane & 15) == 0) {
        als[wid * 4 + hd] = ps;
        ald[wid * 4 + hd] = pd;
    }
}

// -------- edge softmax numerators in CSR order: p[i][h] = exp(lrelu(als+ald)) --------
__global__ void edge_logit_kernel(const float* __restrict__ als, const float* __restrict__ ald,
                                  const int* __restrict__ csr_src, const int* __restrict__ csr_dst,
                                  float* __restrict__ p_arr) {
    int i = blockIdx.x * blockDim.x + threadIdx.x;
    if (i >= N_EDGES) return;
    int s = csr_src[i], d = csr_dst[i];
    float4 as = *(const float4*)&als[s * 4];
    float4 ad = *(const float4*)&ald[d * 4];
    float4 ev;
    ev.x = __expf(lrelu(as.x + ad.x));
    ev.y = __expf(lrelu(as.y + ad.y));
    ev.z = __expf(lrelu(as.z + ad.z));
    ev.w = __expf(lrelu(as.w + ad.w));
    *(float4*)&p_arr[i * 4] = ev;
}

// ------- per-dst single-pass aggregation + bias + ELU; writes hi/lo bf16 ----
__global__ void aggregate_kernel(const __half* __restrict__ hg, const float* __restrict__ als,
                                 const float* __restrict__ ald_, const int* __restrict__ rowptr,
                                 const int* __restrict__ csr_src, const float* __restrict__ p_arr,
                                 const float* __restrict__ bias, short* __restrict__ ohi,
                                 short* __restrict__ olo) {
    int n = (blockIdx.x * blockDim.x + threadIdx.x) >> 6;
    int lane = threadIdx.x & 63;
    if (n >= N_NODES) return;
    int hd = lane >> 4;
    int c0 = lane << 2;

    float p_self = __expf(lrelu(als[n * 4 + hd] + ald_[n * 4 + hd]));
    ushort4 su = *(const ushort4*)&hg[(size_t)n * WIDTH_ + c0];
    float a0 = p_self * h2f(su.x), a1 = p_self * h2f(su.y);
    float a2 = p_self * h2f(su.z), a3 = p_self * h2f(su.w);
    float denom = p_self;

    int rs = rowptr[n], re = rowptr[n + 1];
    int i = rs;
    float w0 = 0.f, w1 = 0.f, w2 = 0.f, w3 = 0.f;
    float x0 = 0.f, x1 = 0.f, x2 = 0.f, x3 = 0.f;
    float y0 = 0.f, y1 = 0.f, y2 = 0.f, y3 = 0.f;
    float z0 = 0.f, z1 = 0.f, z2 = 0.f, z3 = 0.f;
    float v0 = 0.f, v1 = 0.f, v2 = 0.f, v3 = 0.f;
    for (; i + 4 <= re; i += 4) {
        int s0 = csr_src[i + 0], s1 = csr_src[i + 1];
        int s2 = csr_src[i + 2], s3 = csr_src[i + 3];
        float p0 = p_arr[(i + 0) * 4 + hd], p1 = p_arr[(i + 1) * 4 + hd];
        float p2 = p_arr[(i + 2) * 4 + hd], p3 = p_arr[(i + 3) * 4 + hd];
        ushort4 u0 = *(const ushort4*)&hg[(size_t)s0 * WIDTH_ + c0];
        ushort4 u1 = *(const ushort4*)&hg[(size_t)s1 * WIDTH_ + c0];
        ushort4 u2 = *(const ushort4*)&hg[(size_t)s2 * WIDTH_ + c0];
        ushort4 u3 = *(const ushort4*)&hg[(size_t)s3 * WIDTH_ + c0];
        x0 += p0 * h2f(u0.x); y0 += p0 * h2f(u0.y); z0 += p0 * h2f(u0.z); v0 += p0 * h2f(u0.w);
        x1 += p1 * h2f(u1.x); y1 += p1 * h2f(u1.y); z1 += p1 * h2f(u1.z); v1 += p1 * h2f(u1.w);
        x2 += p2 * h2f(u2.x); y2 += p2 * h2f(u2.y); z2 += p2 * h2f(u2.z); v2 += p2 * h2f(u2.w);
        x3 += p3 * h2f(u3.x); y3 += p3 * h2f(u3.y); z3 += p3 * h2f(u3.z); v3 += p3 * h2f(u3.w);
        w0 += p0; w1 += p1; w2 += p2; w3 += p3;
    }
    for (; i < re; ++i) {
        int s = csr_src[i];
        float p = p_arr[i * 4 + hd];
        ushort4 u = *(const ushort4*)&hg[(size_t)s * WIDTH_ + c0];
        x0 += p * h2f(u.x); y0 += p * h2f(u.y); z0 += p * h2f(u.z); v0 += p * h2f(u.w);
        w0 += p;
    }
    a0 += (x0 + x1) + (x2 + x3);
    a1 += (y0 + y1) + (y2 + y3);
    a2 += (z0 + z1) + (z2 + z3);
    a3 += (v0 + v1) + (v2 + v3);
    denom += (w0 + w1) + (w2 + w3);

    float inv = 1.0f / (denom + 1e-16f);
    float r0 = a0 * inv + bias[c0 + 0];
    float r1 = a1 * inv + bias[c0 + 1];
    float r2 = a2 * inv + bias[c0 + 2];
    float r3 = a3 * inv + bias[c0 + 3];
    r0 = (r0 > 0.f) ? r0 : (__expf(r0) - 1.f);
    r1 = (r1 > 0.f) ? r1 : (__expf(r1) - 1.f);
    r2 = (r2 > 0.f) ? r2 : (__expf(r2) - 1.f);
    r3 = (r3 > 0.f) ? r3 : (__expf(r3) - 1.f);
    short4 h, l;
    split1(r0, h.x, l.x);
    split1(r1, h.y, l.y);
    split1(r2, h.z, l.z);
    split1(r3, h.w, l.w);
    *(short4*)&ohi[(size_t)n * WIDTH_ + c0] = h;
    *(short4*)&olo[(size_t)n * WIDTH_ + c0] = l;
}

// ---------------- final pool ----------------
__global__ void out_init_kernel(const float* __restrict__ lin_b, float* __restrict__ out) {
    out[threadIdx.x] = lin_b[0];
}

__global__ void pool_kernel(const short* __restrict__ hhi, const short* __restrict__ hlo,
                            const float* __restrict__ lin_w, const int* __restrict__ batch,
                            float* __restrict__ out) {
    __shared__ float acc[NUM_GRAPHS_];
    int t = threadIdx.x;
    acc[t] = 0.f;
    __syncthreads();
    int wid = t >> 6, lane = t & 63;
    int n0 = blockIdx.x * 64;
    float4 wv = *(const float4*)&lin_w[lane << 2];
    for (int n = n0 + wid; n < n0 + 64; n += 4) {
        if (n >= N_NODES) break;
        short4 vh = *(const short4*)&hhi[(size_t)n * WIDTH_ + (lane << 2)];
        short4 vl = *(const short4*)&hlo[(size_t)n * WIDTH_ + (lane << 2)];
        float p = join1(vh.x, vl.x) * wv.x + join1(vh.y, vl.y) * wv.y +
                  join1(vh.z, vl.z) * wv.z + join1(vh.w, vl.w) * wv.w;
        for (int off = 1; off < 64; off <<= 1) p += __shfl_xor(p, off);
        if (lane == 0) atomicAdd(&acc[batch[n]], p);
    }
    __syncthreads();
    float v = acc[t];
    if (v != 0.f) atomicAdd(&out[t], v);
}

extern "C" void kernel_launch(void* const* d_in, const int* in_sizes, int n_in,
                              void* d_out, int out_size, void* d_ws, size_t ws_size,
                              hipStream_t stream) {
    const float* x = (const float*)d_in[0];
    const int* edge_index = (const int*)d_in[1];
    const int* batch = (const int*)d_in[3];
    const float* W0 = (const float*)d_in[4];
    const float* a_src0 = (const float*)d_in[5];
    const float* a_dst0 = (const float*)d_in[6];
    const float* b0 = (const float*)d_in[7];
    const float* W1 = (const float*)d_in[8];
    const float* a_src1 = (const float*)d_in[9];
    const float* a_dst1 = (const float*)d_in[10];
    const float* b1 = (const float*)d_in[11];
    const float* W2 = (const float*)d_in[12];
    const float* a_src2 = (const float*)d_in[13];
    const float* a_dst2 = (const float*)d_in[14];
    const float* b2 = (const float*)d_in[15];
    const float* lin_w = (const float*)d_in[16];
    const float* lin_b = (const float*)d_in[17];
    float* out = (float*)d_out;

    const int* e_src = edge_index;
    const int* e_dst = edge_index + N_EDGES;

    // ---- workspace layout ----
    char* p = (char*)d_ws;
    __half* hG = (__half*)p;              p += (size_t)HROW * WIDTH_ * 2;   // 25.6 MB
    short* hBhi = (short*)p;              p += (size_t)HROW * WIDTH_ * 2;   // 25.6 MB
    short* hBlo = (short*)p;              p += (size_t)HROW * WIDTH_ * 2;   // 25.6 MB
    short* Wt0h = (short*)p;              p += 256 * IN_DIM_ * 2;
    short* Wt0l = (short*)p;              p += 256 * IN_DIM_ * 2;
    short* Wt1h = (short*)p;              p += 256 * WIDTH_ * 2;
    short* Wt1l = (short*)p;              p += 256 * WIDTH_ * 2;
    short* Wt2h = (short*)p;              p += 256 * WIDTH_ * 2;
    short* Wt2l = (short*)p;              p += 256 * WIDTH_ * 2;
    float* als = (float*)p;               p += (size_t)HROW * 4 * 4;
    float* ald = (float*)p;               p += (size_t)HROW * 4 * 4;
    float* p_arr = (float*)p;             p += (size_t)N_EDGES * 4 * 4;     // 6.4 MB
    int* deg = (int*)p;                   p += HROW * 4;
    int* rowptr = (int*)p;                p += (HROW + 4) * 4;
    int* cursor = (int*)p;                p += HROW * 4;
    int* csr_src = (int*)p;               p += (size_t)N_EDGES * 4;
    int* csr_dst = (int*)p;               p += (size_t)N_EDGES * 4;
    int* partials = (int*)p;              p += 256 * 4;
    // x splits alias hBhi (dead before aggregate layer 0 writes hB)
    short* xhi = hBhi;
    short* xlo = hBhi + (size_t)HROW * IN_DIM_;

    // ---- CSR build ----
    hipMemsetAsync(deg, 0, HROW * sizeof(int), stream);
    hipMemsetAsync(cursor, 0, HROW * sizeof(int), stream);
    hist_kernel<<<(N_EDGES + 255) / 256, 256, 0, stream>>>(e_dst, deg);
    const int NB1 = (N_NODES + 255) / 256;
    scan1_kernel<<<NB1, 256, 0, stream>>>(deg, rowptr, partials);
    scan2_kernel<<<1, 256, 0, stream>>>(partials, NB1);
    scan3_kernel<<<NB1, 256, 0, stream>>>(rowptr, partials);
    scatter_kernel<<<(N_EDGES + 255) / 256, 256, 0, stream>>>(e_src, e_dst, rowptr, cursor,
                                                              csr_src, csr_dst);

    // ---- weight splits ----
    wsplit_kernel<<<IN_DIM_, 256, 0, stream>>>(W0, Wt0h, Wt0l, IN_DIM_);
    wsplit_kernel<<<WIDTH_, 256, 0, stream>>>(W1, Wt1h, Wt1l, WIDTH_);
    wsplit_kernel<<<WIDTH_, 256, 0, stream>>>(W2, Wt2h, Wt2l, WIDTH_);
    // ---- x split ----
    split4_kernel<IN_DIM_><<<(HROW * IN_DIM_ / 4 + 255) / 256, 256, 0, stream>>>(x, xhi, xlo);

    const int NWB = (N_NODES + 3) / 4;
    const int NEB = (N_EDGES + 255) / 256;

    // layer 0
    mfma_gemm<IN_DIM_><<<NWG_GEMM, 64, 0, stream>>>(xhi, xlo, Wt0h, Wt0l, hG);
    al_kernel<<<NWB, 256, 0, stream>>>(hG, a_src0, a_dst0, als, ald);
    edge_logit_kernel<<<NEB, 256, 0, stream>>>(als, ald, csr_src, csr_dst, p_arr);
    aggregate_kernel<<<NWB, 256, 0, stream>>>(hG, als, ald, rowptr, csr_src, p_arr, b0, hBhi,
                                              hBlo);
    // layer 1
    mfma_gemm<WIDTH_><<<NWG_GEMM, 64, 0, stream>>>(hBhi, hBlo, Wt1h, Wt1l, hG);
    al_kernel<<<NWB, 256, 0, stream>>>(hG, a_src1, a_dst1, als, ald);
    edge_logit_kernel<<<NEB, 256, 0, stream>>>(als, ald, csr_src, csr_dst, p_arr);
    aggregate_kernel<<<NWB, 256, 0, stream>>>(hG, als, ald, rowptr, csr_src, p_arr, b1, hBhi,
                                              hBlo);
    // layer 2
    mfma_gemm<WIDTH_><<<NWG_GEMM, 64, 0, stream>>>(hBhi, hBlo, Wt2h, Wt2l, hG);
    al_kernel<<<NWB, 256, 0, stream>>>(hG, a_src2, a_dst2, als, ald);
    edge_logit_kernel<<<NEB, 256, 0, stream>>>(als, ald, csr_src, csr_dst, p_arr);
    aggregate_kernel<<<NWB, 256, 0, stream>>>(hG, als, ald, rowptr, csr_src, p_arr, b2, hBhi,
                                              hBlo);

    // ---- pool + linear ----
    out_init_kernel<<<1, 256, 0, stream>>>(lin_b, out);
    pool_kernel<<<(N_NODES + 63) / 64, 256, 0, stream>>>(hBhi, hBlo, lin_w, batch, out);
}